// Round 1
// baseline (767.124 us; speedup 1.0000x reference)
//
#include <hip/hip_runtime.h>
#include <hip/hip_bf16.h>

#define T_TOT   4096
#define NH      32
#define NKV     8
#define GQ      4
#define DHEAD   128
#define NSLOTS  8192
#define QBLK    16
#define KVBLK   32
#define ATT_SCALE 0.088388347648318447f

typedef __attribute__((ext_vector_type(8))) short bf16x8;
typedef __attribute__((ext_vector_type(4))) float f32x4;

__device__ __forceinline__ unsigned short f2bf(float f) {
    union { float f; unsigned u; } x; x.f = f;
    unsigned r = x.u + 0x7fffu + ((x.u >> 16) & 1u);
    return (unsigned short)(r >> 16);
}

__device__ __forceinline__ unsigned long long pack4bf(float a, float b, float c, float d) {
    unsigned lo = (unsigned)f2bf(a) | ((unsigned)f2bf(b) << 16);
    unsigned hi = (unsigned)f2bf(c) | ((unsigned)f2bf(d) << 16);
    return (unsigned long long)lo | ((unsigned long long)hi << 32);
}

// ---------------- cache copy + scatter ----------------

__global__ __launch_bounds__(256) void copy_cache(const float4* __restrict__ kc,
                                                  const float4* __restrict__ vc,
                                                  float4* __restrict__ kco,
                                                  float4* __restrict__ vco) {
    int idx = blockIdx.x * 256 + threadIdx.x;  // exactly NSLOTS*NKV*DHEAD/4 threads
    kco[idx] = kc[idx];
    vco[idx] = vc[idx];
}

__global__ __launch_bounds__(256) void scatter_kv(const float4* __restrict__ k,
                                                  const float4* __restrict__ v,
                                                  const int* __restrict__ slot_map,
                                                  float4* __restrict__ kco,
                                                  float4* __restrict__ vco) {
    int idx = blockIdx.x * 256 + threadIdx.x;  // T_TOT*NKV*DHEAD/4 threads
    int tok = idx >> 8;                        // NKV*DHEAD/4 = 256 float4 per token
    int j   = idx & 255;
    int slot = slot_map[tok];
    if (slot >= 0 && slot < NSLOTS) {
        size_t dst = (size_t)slot * 256 + j;
        kco[dst] = k[idx];
        vco[dst] = v[idx];
    }
}

// ---------------- flash attention ----------------

__global__ __launch_bounds__(256) void attn_kernel(const float* __restrict__ qg,
                                                   const float* __restrict__ kg,
                                                   const float* __restrict__ vg,
                                                   const int* __restrict__ cu,
                                                   float* __restrict__ outg)
{
    // K tile: 32 keys x 128 d bf16, row stride 256 B, XOR-swizzled (bits 4..6 by row&7)
    __shared__ __align__(16) char Klds[KVBLK * 256];
    // V tile transposed: 128 d x 32 keys bf16, row stride 64 B, XOR-swizzled (bits 4..5 by d&3)
    __shared__ __align__(16) char Vtlds[DHEAD * 64];
    // P per wave: 16 q x 32 keys bf16, row stride 64 B, swizzled
    __shared__ __align__(16) char Plds[4][QBLK * 64];

    const int tid  = threadIdx.x;
    const int wave = tid >> 6;
    const int lane = tid & 63;
    const int q16  = lane & 15;
    const int grp  = lane >> 4;
    const int kvh  = blockIdx.y;
    const int head = kvh * GQ + wave;
    const int tok0 = blockIdx.x * QBLK;

    int seq_start = 0;
    #pragma unroll
    for (int b = 0; b < 4; ++b) {
        int c0 = cu[b], c1 = cu[b + 1];
        if (tok0 >= c0 && tok0 < c1) seq_start = c0;
    }
    const int p0 = tok0 - seq_start;

    // Preload Q fragments: A-frag lane l holds row (l&15), k = (l>>4)*8 + j
    bf16x8 qf[4];
    {
        const float* qp = qg + ((size_t)(tok0 + q16) * NH + head) * DHEAD + grp * 8;
        #pragma unroll
        for (int c = 0; c < 4; ++c) {
            float4 a = *(const float4*)(qp + c * 32);
            float4 b = *(const float4*)(qp + c * 32 + 4);
            union { bf16x8 v; unsigned long long q[2]; } u;
            u.q[0] = pack4bf(a.x, a.y, a.z, a.w);
            u.q[1] = pack4bf(b.x, b.y, b.z, b.w);
            qf[c] = u.v;
        }
    }

    f32x4 oacc[8];
    #pragma unroll
    for (int n = 0; n < 8; ++n) oacc[n] = (f32x4){0.f, 0.f, 0.f, 0.f};
    float mrow[4] = {-1e30f, -1e30f, -1e30f, -1e30f};
    float lrow[4] = {0.f, 0.f, 0.f, 0.f};

    const int ntiles = (p0 + QBLK + KVBLK - 1) / KVBLK;
    char* Pw = Plds[wave];

    for (int t = 0; t < ntiles; ++t) {
        const int k0 = t * KVBLK;
        __syncthreads();
        // ---- stage K (swizzled) and V (transposed, swizzled), f32 -> bf16 ----
        #pragma unroll
        for (int i = 0; i < 4; ++i) {
            int idx = tid + i * 256;     // 0..1023 : 32 keys x 32 float4
            int key = idx >> 5;
            int d4  = idx & 31;
            size_t gofs = ((size_t)(seq_start + k0 + key) * NKV + kvh) * DHEAD + d4 * 4;
            float4 kvec = *(const float4*)(kg + gofs);
            *(unsigned long long*)(Klds + key * 256 + ((d4 * 8) ^ ((key & 7) << 4))) =
                pack4bf(kvec.x, kvec.y, kvec.z, kvec.w);
            float4 vvec = *(const float4*)(vg + gofs);
            float vf4[4] = {vvec.x, vvec.y, vvec.z, vvec.w};
            #pragma unroll
            for (int j = 0; j < 4; ++j) {
                int dr = d4 * 4 + j;
                *(unsigned short*)(Vtlds + dr * 64 + ((key * 2) ^ ((dr & 3) << 4))) = f2bf(vf4[j]);
            }
        }
        __syncthreads();

        // ---- QK^T : 2 key sub-tiles x 4 d-chunks ----
        float sv[2][4];
        #pragma unroll
        for (int kt = 0; kt < 2; ++kt) {
            f32x4 sacc = (f32x4){0.f, 0.f, 0.f, 0.f};
            int row = kt * 16 + q16;
            #pragma unroll
            for (int c = 0; c < 4; ++c) {
                bf16x8 kf = *(bf16x8*)(Klds + row * 256 + ((c * 64 + grp * 16) ^ ((row & 7) << 4)));
                sacc = __builtin_amdgcn_mfma_f32_16x16x32_bf16(qf[c], kf, sacc, 0, 0, 0);
            }
            int kpos = k0 + kt * 16 + q16;   // C/D col = lane&15 = key
            #pragma unroll
            for (int r = 0; r < 4; ++r) {
                int qpos = p0 + grp * 4 + r; // C/D row = (lane>>4)*4 + reg = q
                sv[kt][r] = (kpos <= qpos) ? sacc[r] * ATT_SCALE : -1e30f;
            }
        }

        // ---- online softmax (16-lane group reductions) + P write ----
        #pragma unroll
        for (int r = 0; r < 4; ++r) {
            float tm = fmaxf(sv[0][r], sv[1][r]);
            #pragma unroll
            for (int mm = 1; mm < 16; mm <<= 1) tm = fmaxf(tm, __shfl_xor(tm, mm));
            float newm = fmaxf(mrow[r], tm);
            float scal = __expf(mrow[r] - newm);
            float e0 = __expf(sv[0][r] - newm);
            float e1 = __expf(sv[1][r] - newm);
            float ps = e0 + e1;
            #pragma unroll
            for (int mm = 1; mm < 16; mm <<= 1) ps += __shfl_xor(ps, mm);
            lrow[r] = lrow[r] * scal + ps;
            mrow[r] = newm;
            #pragma unroll
            for (int n = 0; n < 8; ++n) oacc[n][r] *= scal;
            int prow = grp * 4 + r;
            *(unsigned short*)(Pw + prow * 64 + ((q16 * 2)        ^ ((prow & 3) << 4))) = f2bf(e0);
            *(unsigned short*)(Pw + prow * 64 + (((16 + q16) * 2) ^ ((prow & 3) << 4))) = f2bf(e1);
        }

        // ---- PV : P (16x32) x V (32x128) ----
        bf16x8 pf = *(bf16x8*)(Pw + q16 * 64 + ((grp * 16) ^ ((q16 & 3) << 4)));
        #pragma unroll
        for (int n = 0; n < 8; ++n) {
            int dr = n * 16 + q16;
            bf16x8 vfr = *(bf16x8*)(Vtlds + dr * 64 + ((grp * 16) ^ ((dr & 3) << 4)));
            oacc[n] = __builtin_amdgcn_mfma_f32_16x16x32_bf16(pf, vfr, oacc[n], 0, 0, 0);
        }
    }

    // ---- epilogue: normalize, store f32 ----
    #pragma unroll
    for (int r = 0; r < 4; ++r) {
        float inv = 1.0f / lrow[r];
        float* op = outg + ((size_t)(tok0 + grp * 4 + r) * NH + head) * DHEAD;
        #pragma unroll
        for (int n = 0; n < 8; ++n) op[n * 16 + q16] = oacc[n][r] * inv;
    }
}

// ---------------- launch ----------------

extern "C" void kernel_launch(void* const* d_in, const int* in_sizes, int n_in,
                              void* d_out, int out_size, void* d_ws, size_t ws_size,
                              hipStream_t stream) {
    const float* q  = (const float*)d_in[0];
    const float* k  = (const float*)d_in[1];
    const float* v  = (const float*)d_in[2];
    const float* kc = (const float*)d_in[3];
    const float* vc = (const float*)d_in[4];
    const int* cu   = (const int*)d_in[5];
    const int* slot = (const int*)d_in[6];

    float* out    = (float*)d_out;
    float* kc_out = out + (size_t)T_TOT * NH * DHEAD;
    float* vc_out = kc_out + (size_t)NSLOTS * NKV * DHEAD;

    // caches: copy originals, then scatter new K/V rows
    copy_cache<<<dim3((NSLOTS * NKV * DHEAD / 4) / 256), dim3(256), 0, stream>>>(
        (const float4*)kc, (const float4*)vc, (float4*)kc_out, (float4*)vc_out);
    scatter_kv<<<dim3((T_TOT * NKV * DHEAD / 4) / 256), dim3(256), 0, stream>>>(
        (const float4*)k, (const float4*)v, slot, (float4*)kc_out, (float4*)vc_out);

    // attention
    attn_kernel<<<dim3(T_TOT / QBLK, NKV), dim3(256), 0, stream>>>(q, k, v, cu, out);
}

// Round 2
// 423.998 us; speedup vs baseline: 1.8093x; 1.8093x over previous
//
#include <hip/hip_runtime.h>
#include <hip/hip_bf16.h>

#define T_TOT   4096
#define NH      32
#define NKV     8
#define GQ      4
#define DHEAD   128
#define NSLOTS  8192
#define QB      64      // q rows per block
#define QW      32      // q rows per wave
#define KVB     64      // keys per kv tile
#define ATT_SCALE 0.088388347648318447f

typedef __attribute__((ext_vector_type(8))) short bf16x8;
typedef __attribute__((ext_vector_type(4))) float f32x4;

__device__ __forceinline__ unsigned short f2bf(float f) {
    union { float f; unsigned u; } x; x.f = f;
    unsigned r = x.u + 0x7fffu + ((x.u >> 16) & 1u);
    return (unsigned short)(r >> 16);
}

__device__ __forceinline__ unsigned long long pack4bf(float a, float b, float c, float d) {
    unsigned lo = (unsigned)f2bf(a) | ((unsigned)f2bf(b) << 16);
    unsigned hi = (unsigned)f2bf(c) | ((unsigned)f2bf(d) << 16);
    return (unsigned long long)lo | ((unsigned long long)hi << 32);
}

// ---------------- cache copy + scatter ----------------

__global__ __launch_bounds__(256) void copy_cache(const float4* __restrict__ kc,
                                                  const float4* __restrict__ vc,
                                                  float4* __restrict__ kco,
                                                  float4* __restrict__ vco) {
    int idx = blockIdx.x * 256 + threadIdx.x;
    kco[idx] = kc[idx];
    vco[idx] = vc[idx];
}

__global__ __launch_bounds__(256) void scatter_kv(const float4* __restrict__ k,
                                                  const float4* __restrict__ v,
                                                  const int* __restrict__ slot_map,
                                                  float4* __restrict__ kco,
                                                  float4* __restrict__ vco) {
    int idx = blockIdx.x * 256 + threadIdx.x;
    int tok = idx >> 8;
    int j   = idx & 255;
    int slot = slot_map[tok];
    if (slot >= 0 && slot < NSLOTS) {
        size_t dst = (size_t)slot * 256 + j;
        kco[dst] = k[idx];
        vco[dst] = v[idx];
    }
}

// ---------------- flash attention ----------------
// Block: 512 threads (8 waves), covers QB=64 q-rows for one kv-head group.
// Wave w: head = kvh*4 + (w>>1), q rows tok0 + (w&1)*32 .. +31 (2 MFMA row-tiles).

__global__ __launch_bounds__(512, 2) void attn_kernel(const float* __restrict__ qg,
                                                      const float* __restrict__ kg,
                                                      const float* __restrict__ vg,
                                                      const int* __restrict__ cu,
                                                      float* __restrict__ outg)
{
    // K: 64 keys x 128 d bf16, row stride 256 B, swizzle byte ^= (key&7)<<4
    __shared__ __align__(16) char Klds[KVB * 256];
    // V^T: 128 d x 64 keys bf16, row stride 128 B, swizzle (k*2) ^ ((d&15)<<3)
    __shared__ __align__(16) char Vt[DHEAD * 128];
    // P per wave: 32 q x 64 k bf16, row stride 128 B, swizzle (k*2) ^ ((q&7)<<4)
    __shared__ __align__(16) char Plds[8][QW * 128];

    const int tid  = threadIdx.x;
    const int wave = tid >> 6;
    const int lane = tid & 63;
    const int q16  = lane & 15;
    const int grp  = lane >> 4;
    const int kvh  = blockIdx.y;
    const int head = kvh * GQ + (wave >> 1);
    const int tok0 = blockIdx.x * QB;
    const int qw0  = tok0 + (wave & 1) * QW;   // first q row of this wave

    int seq_start = 0;
    #pragma unroll
    for (int b = 0; b < 4; ++b) {
        int c0 = cu[b], c1 = cu[b + 1];
        if (tok0 >= c0 && tok0 < c1) seq_start = c0;
    }
    const int p0  = tok0 - seq_start;          // block q offset (multiple of 64)
    const int pw0 = p0 + (wave & 1) * QW;      // wave q offset
    const int ntiles = p0 / KVB + 1;

    // Q fragments: A-frag lane l -> row (l&15), k = (l>>4)*8 + j
    bf16x8 qf[2][4];
    {
        const float* qp = qg + ((size_t)(qw0 + q16) * NH + head) * DHEAD + grp * 8;
        #pragma unroll
        for (int qt = 0; qt < 2; ++qt) {
            #pragma unroll
            for (int c = 0; c < 4; ++c) {
                const float* p = qp + (size_t)qt * 16 * NH * DHEAD + c * 32;
                float4 a = *(const float4*)(p);
                float4 b = *(const float4*)(p + 4);
                union { bf16x8 v; unsigned long long q[2]; } u;
                u.q[0] = pack4bf(a.x, a.y, a.z, a.w);
                u.q[1] = pack4bf(b.x, b.y, b.z, b.w);
                qf[qt][c] = u.v;
            }
        }
    }

    f32x4 oacc[2][8];
    #pragma unroll
    for (int qt = 0; qt < 2; ++qt)
        #pragma unroll
        for (int n = 0; n < 8; ++n) oacc[qt][n] = (f32x4){0.f, 0.f, 0.f, 0.f};
    float mrow[2][4], lrow[2][4];
    #pragma unroll
    for (int qt = 0; qt < 2; ++qt)
        #pragma unroll
        for (int r = 0; r < 4; ++r) { mrow[qt][r] = -1e30f; lrow[qt][r] = 0.f; }

    char* Pw = Plds[wave];

    for (int t = 0; t < ntiles; ++t) {
        const int k0 = t * KVB;
        __syncthreads();
        // ---- stage K: 64 keys x 32 float4, vectorized 8-B swizzled writes ----
        #pragma unroll
        for (int i = 0; i < 4; ++i) {
            int idx = tid + i * 512;
            int key = idx >> 5;
            int d4  = idx & 31;
            float4 kv4 = *(const float4*)(kg +
                ((size_t)(seq_start + k0 + key) * NKV + kvh) * DHEAD + d4 * 4);
            *(unsigned long long*)(Klds + key * 256 + ((d4 * 8) ^ ((key & 7) << 4))) =
                pack4bf(kv4.x, kv4.y, kv4.z, kv4.w);
        }
        // ---- stage V^T: each thread: 1 d-row, 4 consecutive keys (scalar loads,
        //      wave address-set still contiguous), one 8-B swizzled write ----
        #pragma unroll
        for (int i = 0; i < 4; ++i) {
            int job = tid + i * 512;
            int kq  = job >> 7;          // key group of 4
            int d   = job & 127;
            const float* vp = vg +
                ((size_t)(seq_start + k0 + kq * 4) * NKV + kvh) * DHEAD + d;
            float c0 = vp[0];
            float c1 = vp[NKV * DHEAD];
            float c2 = vp[2 * NKV * DHEAD];
            float c3 = vp[3 * NKV * DHEAD];
            *(unsigned long long*)(Vt + d * 128 + ((kq * 8) ^ ((d & 15) << 3))) =
                pack4bf(c0, c1, c2, c3);
        }
        __syncthreads();

        // ---- QK^T: 4 key-subtiles x 4 d-chunks, both q row-tiles ----
        float sv[2][4][4];
        const bool lastt = (t == ntiles - 1);
        #pragma unroll
        for (int ktile = 0; ktile < 4; ++ktile) {
            f32x4 sacc0 = (f32x4){0.f, 0.f, 0.f, 0.f};
            f32x4 sacc1 = (f32x4){0.f, 0.f, 0.f, 0.f};
            int row = ktile * 16 + q16;
            #pragma unroll
            for (int c = 0; c < 4; ++c) {
                bf16x8 kf = *(bf16x8*)(Klds + row * 256 +
                                       ((c * 64 + grp * 16) ^ ((row & 7) << 4)));
                sacc0 = __builtin_amdgcn_mfma_f32_16x16x32_bf16(qf[0][c], kf, sacc0, 0, 0, 0);
                sacc1 = __builtin_amdgcn_mfma_f32_16x16x32_bf16(qf[1][c], kf, sacc1, 0, 0, 0);
            }
            if (lastt) {
                int kpos = k0 + ktile * 16 + q16;
                #pragma unroll
                for (int r = 0; r < 4; ++r) {
                    int qp0 = pw0 + grp * 4 + r;
                    sv[0][ktile][r] = (kpos <= qp0)      ? sacc0[r] * ATT_SCALE : -1e30f;
                    sv[1][ktile][r] = (kpos <= qp0 + 16) ? sacc1[r] * ATT_SCALE : -1e30f;
                }
            } else {
                #pragma unroll
                for (int r = 0; r < 4; ++r) {
                    sv[0][ktile][r] = sacc0[r] * ATT_SCALE;
                    sv[1][ktile][r] = sacc1[r] * ATT_SCALE;
                }
            }
        }

        // ---- online softmax (16-lane reductions), write P (swizzled) ----
        #pragma unroll
        for (int qt = 0; qt < 2; ++qt) {
            #pragma unroll
            for (int r = 0; r < 4; ++r) {
                float tm = fmaxf(fmaxf(sv[qt][0][r], sv[qt][1][r]),
                                 fmaxf(sv[qt][2][r], sv[qt][3][r]));
                #pragma unroll
                for (int mm = 1; mm < 16; mm <<= 1) tm = fmaxf(tm, __shfl_xor(tm, mm));
                float newm = fmaxf(mrow[qt][r], tm);
                float scal = __expf(mrow[qt][r] - newm);
                float ps = 0.f;
                int qrow = qt * 16 + grp * 4 + r;
                #pragma unroll
                for (int ktile = 0; ktile < 4; ++ktile) {
                    float e = __expf(sv[qt][ktile][r] - newm);
                    ps += e;
                    int key = ktile * 16 + q16;
                    *(unsigned short*)(Pw + qrow * 128 +
                        ((key * 2) ^ ((qrow & 7) << 4))) = f2bf(e);
                }
                #pragma unroll
                for (int mm = 1; mm < 16; mm <<= 1) ps += __shfl_xor(ps, mm);
                lrow[qt][r] = lrow[qt][r] * scal + ps;
                mrow[qt][r] = newm;
                #pragma unroll
                for (int n = 0; n < 8; ++n) oacc[qt][n][r] *= scal;
            }
        }

        // ---- PV: P(32x64) x V(64x128) ----
        #pragma unroll
        for (int kt = 0; kt < 2; ++kt) {
            bf16x8 pf[2];
            #pragma unroll
            for (int qt = 0; qt < 2; ++qt) {
                int qrow = qt * 16 + q16;
                pf[qt] = *(bf16x8*)(Pw + qrow * 128 +
                                    ((kt * 64 + grp * 16) ^ ((qrow & 7) << 4)));
            }
            #pragma unroll
            for (int n = 0; n < 8; ++n) {
                int d = n * 16 + q16;
                int kq0 = kt * 8 + grp * 2;
                union { bf16x8 v8; unsigned long long q[2]; } uv;
                uv.q[0] = *(unsigned long long*)(Vt + d * 128 + ((kq0 * 8) ^ ((d & 15) << 3)));
                uv.q[1] = *(unsigned long long*)(Vt + d * 128 + (((kq0 + 1) * 8) ^ ((d & 15) << 3)));
                oacc[0][n] = __builtin_amdgcn_mfma_f32_16x16x32_bf16(pf[0], uv.v8, oacc[0][n], 0, 0, 0);
                oacc[1][n] = __builtin_amdgcn_mfma_f32_16x16x32_bf16(pf[1], uv.v8, oacc[1][n], 0, 0, 0);
            }
        }
    }

    // ---- epilogue ----
    #pragma unroll
    for (int qt = 0; qt < 2; ++qt) {
        #pragma unroll
        for (int r = 0; r < 4; ++r) {
            float inv = 1.0f / lrow[qt][r];
            float* op = outg + ((size_t)(qw0 + qt * 16 + grp * 4 + r) * NH + head) * DHEAD;
            #pragma unroll
            for (int n = 0; n < 8; ++n) op[n * 16 + q16] = oacc[qt][n][r] * inv;
        }
    }
}

// ---------------- launch ----------------

extern "C" void kernel_launch(void* const* d_in, const int* in_sizes, int n_in,
                              void* d_out, int out_size, void* d_ws, size_t ws_size,
                              hipStream_t stream) {
    const float* q  = (const float*)d_in[0];
    const float* k  = (const float*)d_in[1];
    const float* v  = (const float*)d_in[2];
    const float* kc = (const float*)d_in[3];
    const float* vc = (const float*)d_in[4];
    const int* cu   = (const int*)d_in[5];
    const int* slot = (const int*)d_in[6];

    float* out    = (float*)d_out;
    float* kc_out = out + (size_t)T_TOT * NH * DHEAD;
    float* vc_out = kc_out + (size_t)NSLOTS * NKV * DHEAD;

    copy_cache<<<dim3((NSLOTS * NKV * DHEAD / 4) / 256), dim3(256), 0, stream>>>(
        (const float4*)kc, (const float4*)vc, (float4*)kc_out, (float4*)vc_out);
    scatter_kv<<<dim3((T_TOT * NKV * DHEAD / 4) / 256), dim3(256), 0, stream>>>(
        (const float4*)k, (const float4*)v, slot, (float4*)kc_out, (float4*)vc_out);

    attn_kernel<<<dim3(T_TOT / QB, NKV), dim3(512), 0, stream>>>(q, k, v, cu, out);
}

// Round 3
// 353.519 us; speedup vs baseline: 2.1700x; 1.1994x over previous
//
#include <hip/hip_runtime.h>
#include <hip/hip_bf16.h>

#define T_TOT   4096
#define NH      32
#define NKV     8
#define GQ      4
#define DHEAD   128
#define NSLOTS  8192
#define QB      64      // q rows per block
#define QW      32      // q rows per wave
#define KVB     64      // keys per kv tile
#define NTILES  (T_TOT / KVB)   // 64 global token tiles
#define ATT_SCALE 0.088388347648318447f

typedef __attribute__((ext_vector_type(8))) short bf16x8;
typedef __attribute__((ext_vector_type(4))) float f32x4;

__device__ __forceinline__ unsigned short f2bf(float f) {
    union { float f; unsigned u; } x; x.f = f;
    unsigned r = x.u + 0x7fffu + ((x.u >> 16) & 1u);
    return (unsigned short)(r >> 16);
}

__device__ __forceinline__ unsigned long long pack4bf(float a, float b, float c, float d) {
    unsigned lo = (unsigned)f2bf(a) | ((unsigned)f2bf(b) << 16);
    unsigned hi = (unsigned)f2bf(c) | ((unsigned)f2bf(d) << 16);
    return (unsigned long long)lo | ((unsigned long long)hi << 32);
}

__device__ __forceinline__ void gload16(const char* g, char* l) {
    __builtin_amdgcn_global_load_lds(
        (const __attribute__((address_space(1))) void*)g,
        (__attribute__((address_space(3))) void*)l,
        16, 0, 0);
}

// longest-first q-block schedule for CU=[0,1024,1920,3072,4096] (perf-only)
__constant__ unsigned char QORD[64] = {
    47,46,15,45,63,14,44,62,13,29,43,61,12,28,42,60,
    11,27,41,59,10,26,40,58, 9,25,39,57, 8,24,38,56,
     7,23,37,55, 6,22,36,54, 5,21,35,53, 4,20,34,52,
     3,19,33,51, 2,18,32,50, 1,17,31,49, 0,16,30,48
};

// ---------------- cache copy + scatter (run AFTER attn) ----------------

__global__ __launch_bounds__(256) void copy_cache(const float4* __restrict__ kc,
                                                  const float4* __restrict__ vc,
                                                  float4* __restrict__ kco,
                                                  float4* __restrict__ vco) {
    int idx = blockIdx.x * 256 + threadIdx.x;
    kco[idx] = kc[idx];
    vco[idx] = vc[idx];
}

__global__ __launch_bounds__(256) void scatter_kv(const float4* __restrict__ k,
                                                  const float4* __restrict__ v,
                                                  const int* __restrict__ slot_map,
                                                  float4* __restrict__ kco,
                                                  float4* __restrict__ vco) {
    int idx = blockIdx.x * 256 + threadIdx.x;
    int tok = idx >> 8;
    int j   = idx & 255;
    int slot = slot_map[tok];
    if (slot >= 0 && slot < NSLOTS) {
        size_t dst = (size_t)slot * 256 + j;
        kco[dst] = k[idx];
        vco[dst] = v[idx];
    }
}

// ---------------- pre-pass: f32 K/V -> pre-swizzled bf16 tiles ----------------
// Kbf tile (16KB): key*256 + ((d4*8) ^ ((key&7)<<4))           [64 keys x 128 d]
// Vbf tile (16KB): d*128   + ((kq*8) ^ ((d&15)<<3))            [128 d x 64 keys]
// tile index: (kvh*64 + token_tile) << 14

__global__ __launch_bounds__(256) void prep_kv(const float* __restrict__ kg,
                                               const float* __restrict__ vg,
                                               char* __restrict__ kbf,
                                               char* __restrict__ vbf) {
    const int tile = blockIdx.x;
    const int kvh  = blockIdx.y;
    const int tid  = threadIdx.x;
    char* kt = kbf + (((size_t)kvh * NTILES + tile) << 14);
    char* vt = vbf + (((size_t)kvh * NTILES + tile) << 14);
    #pragma unroll
    for (int it = 0; it < 8; ++it) {
        int idx = tid + it * 256;
        int key = idx >> 5, d4 = idx & 31;
        float4 x = *(const float4*)(kg +
            ((size_t)(tile * 64 + key) * NKV + kvh) * DHEAD + d4 * 4);
        *(unsigned long long*)(kt + key * 256 + ((d4 * 8) ^ ((key & 7) << 4))) =
            pack4bf(x.x, x.y, x.z, x.w);
    }
    #pragma unroll
    for (int it = 0; it < 8; ++it) {
        int job = tid + it * 256;
        int kq = job >> 7, d = job & 127;
        const float* vp = vg +
            ((size_t)(tile * 64 + kq * 4) * NKV + kvh) * DHEAD + d;
        *(unsigned long long*)(vt + d * 128 + ((kq * 8) ^ ((d & 15) << 3))) =
            pack4bf(vp[0], vp[NKV * DHEAD], vp[2 * NKV * DHEAD], vp[3 * NKV * DHEAD]);
    }
}

// ---------------- flash attention ----------------

__global__ __launch_bounds__(512, 2) void attn_kernel(const float* __restrict__ qg,
                                                      const char* __restrict__ kbf,
                                                      const char* __restrict__ vbf,
                                                      const int* __restrict__ cu,
                                                      float* __restrict__ outg)
{
    __shared__ __align__(16) char Klds[KVB * 256];      // 16KB, swizzled copy
    __shared__ __align__(16) char Vt[DHEAD * 128];      // 16KB, swizzled copy
    __shared__ __align__(16) char Plds[8][QW * 128];    // 32KB

    const int tid  = threadIdx.x;
    const int wave = tid >> 6;
    const int lane = tid & 63;
    const int q16  = lane & 15;
    const int grp  = lane >> 4;
    const int bid  = blockIdx.x;
    const int qblk = QORD[bid >> 3];
    const int kvh  = bid & 7;
    const int head = kvh * GQ + (wave >> 1);
    const int tok0 = qblk * QB;
    const int qw0  = tok0 + (wave & 1) * QW;

    int seq_start = 0;
    #pragma unroll
    for (int b = 0; b < 4; ++b) {
        int c0 = cu[b], c1 = cu[b + 1];
        if (tok0 >= c0 && tok0 < c1) seq_start = c0;
    }
    const int p0  = tok0 - seq_start;
    const int pw0 = p0 + (wave & 1) * QW;
    const int ntiles = p0 / KVB + 1;
    const int tile0 = seq_start >> 6;          // global token-tile of key 0

    // Q fragments (f32 -> bf16 once per block)
    bf16x8 qf[2][4];
    {
        const float* qp = qg + ((size_t)(qw0 + q16) * NH + head) * DHEAD + grp * 8;
        #pragma unroll
        for (int qt = 0; qt < 2; ++qt) {
            #pragma unroll
            for (int c = 0; c < 4; ++c) {
                const float* p = qp + (size_t)qt * 16 * NH * DHEAD + c * 32;
                float4 a = *(const float4*)(p);
                float4 b = *(const float4*)(p + 4);
                union { bf16x8 v; unsigned long long q[2]; } u;
                u.q[0] = pack4bf(a.x, a.y, a.z, a.w);
                u.q[1] = pack4bf(b.x, b.y, b.z, b.w);
                qf[qt][c] = u.v;
            }
        }
    }

    f32x4 oacc[2][8];
    #pragma unroll
    for (int qt = 0; qt < 2; ++qt)
        #pragma unroll
        for (int n = 0; n < 8; ++n) oacc[qt][n] = (f32x4){0.f, 0.f, 0.f, 0.f};
    float mrow[2][4], lrow[2][4];
    #pragma unroll
    for (int qt = 0; qt < 2; ++qt)
        #pragma unroll
        for (int r = 0; r < 4; ++r) { mrow[qt][r] = -1e30f; lrow[qt][r] = 0.f; }

    char* Pw = Plds[wave];
    const int wbase = wave * 2048;

    for (int t = 0; t < ntiles; ++t) {
        const int k0 = t * KVB;
        const char* gK = kbf + (((size_t)kvh * NTILES + tile0 + t) << 14);
        const char* gV = vbf + (((size_t)kvh * NTILES + tile0 + t) << 14);
        __syncthreads();
        // ---- stage K + V^T: pure async 16B copies (pre-swizzled source) ----
        #pragma unroll
        for (int i = 0; i < 2; ++i) {
            gload16(gK + wbase + i * 1024 + lane * 16, Klds + wbase + i * 1024);
            gload16(gV + wbase + i * 1024 + lane * 16, Vt   + wbase + i * 1024);
        }
        __syncthreads();   // compiler drains vmcnt(0) before barrier

        // ---- QK^T ----
        float sv[2][4][4];
        const bool lastt = (t == ntiles - 1);
        __builtin_amdgcn_s_setprio(1);
        #pragma unroll
        for (int ktile = 0; ktile < 4; ++ktile) {
            f32x4 sacc0 = (f32x4){0.f, 0.f, 0.f, 0.f};
            f32x4 sacc1 = (f32x4){0.f, 0.f, 0.f, 0.f};
            int row = ktile * 16 + q16;
            #pragma unroll
            for (int c = 0; c < 4; ++c) {
                bf16x8 kf = *(bf16x8*)(Klds + row * 256 +
                                       ((c * 64 + grp * 16) ^ ((row & 7) << 4)));
                sacc0 = __builtin_amdgcn_mfma_f32_16x16x32_bf16(qf[0][c], kf, sacc0, 0, 0, 0);
                sacc1 = __builtin_amdgcn_mfma_f32_16x16x32_bf16(qf[1][c], kf, sacc1, 0, 0, 0);
            }
            if (lastt) {
                int kpos = k0 + ktile * 16 + q16;
                #pragma unroll
                for (int r = 0; r < 4; ++r) {
                    int qp0 = pw0 + grp * 4 + r;
                    sv[0][ktile][r] = (kpos <= qp0)      ? sacc0[r] * ATT_SCALE : -1e30f;
                    sv[1][ktile][r] = (kpos <= qp0 + 16) ? sacc1[r] * ATT_SCALE : -1e30f;
                }
            } else {
                #pragma unroll
                for (int r = 0; r < 4; ++r) {
                    sv[0][ktile][r] = sacc0[r] * ATT_SCALE;
                    sv[1][ktile][r] = sacc1[r] * ATT_SCALE;
                }
            }
        }
        __builtin_amdgcn_s_setprio(0);

        // ---- online softmax with deferred rescale (T13, THR=8) ----
        #pragma unroll
        for (int qt = 0; qt < 2; ++qt) {
            #pragma unroll
            for (int r = 0; r < 4; ++r) {
                float tm = fmaxf(fmaxf(sv[qt][0][r], sv[qt][1][r]),
                                 fmaxf(sv[qt][2][r], sv[qt][3][r]));
                #pragma unroll
                for (int mm = 1; mm < 16; mm <<= 1) tm = fmaxf(tm, __shfl_xor(tm, mm));
                if (__any(tm > mrow[qt][r] + 8.0f)) {
                    float newm = fmaxf(tm, mrow[qt][r]);
                    float scal = __expf(mrow[qt][r] - newm);
                    mrow[qt][r] = newm;
                    lrow[qt][r] *= scal;
                    #pragma unroll
                    for (int n = 0; n < 8; ++n) oacc[qt][n][r] *= scal;
                }
                float m = mrow[qt][r];
                float ps = 0.f;
                int qrow = qt * 16 + grp * 4 + r;
                #pragma unroll
                for (int kt2 = 0; kt2 < 4; ++kt2) {
                    float e = __expf(sv[qt][kt2][r] - m);
                    ps += e;
                    *(unsigned short*)(Pw + qrow * 128 +
                        (((kt2 * 16 + q16) * 2) ^ ((qrow & 7) << 4))) = f2bf(e);
                }
                #pragma unroll
                for (int mm = 1; mm < 16; mm <<= 1) ps += __shfl_xor(ps, mm);
                lrow[qt][r] += ps;
            }
        }

        // ---- PV ----
        __builtin_amdgcn_s_setprio(1);
        #pragma unroll
        for (int kt = 0; kt < 2; ++kt) {
            bf16x8 pf[2];
            #pragma unroll
            for (int qt = 0; qt < 2; ++qt) {
                int qrow = qt * 16 + q16;
                pf[qt] = *(bf16x8*)(Pw + qrow * 128 +
                                    ((kt * 64 + grp * 16) ^ ((qrow & 7) << 4)));
            }
            #pragma unroll
            for (int n = 0; n < 8; ++n) {
                int d = n * 16 + q16;
                int kq0 = kt * 8 + grp * 2;
                union { bf16x8 v8; unsigned long long q[2]; } uv;
                uv.q[0] = *(unsigned long long*)(Vt + d * 128 + ((kq0 * 8) ^ ((d & 15) << 3)));
                uv.q[1] = *(unsigned long long*)(Vt + d * 128 + (((kq0 + 1) * 8) ^ ((d & 15) << 3)));
                oacc[0][n] = __builtin_amdgcn_mfma_f32_16x16x32_bf16(pf[0], uv.v8, oacc[0][n], 0, 0, 0);
                oacc[1][n] = __builtin_amdgcn_mfma_f32_16x16x32_bf16(pf[1], uv.v8, oacc[1][n], 0, 0, 0);
            }
        }
        __builtin_amdgcn_s_setprio(0);
    }

    // ---- epilogue ----
    #pragma unroll
    for (int qt = 0; qt < 2; ++qt) {
        #pragma unroll
        for (int r = 0; r < 4; ++r) {
            float inv = 1.0f / lrow[qt][r];
            float* op = outg + ((size_t)(qw0 + qt * 16 + grp * 4 + r) * NH + head) * DHEAD;
            #pragma unroll
            for (int n = 0; n < 8; ++n) op[n * 16 + q16] = oacc[qt][n][r] * inv;
        }
    }
}

// ---------------- launch ----------------

extern "C" void kernel_launch(void* const* d_in, const int* in_sizes, int n_in,
                              void* d_out, int out_size, void* d_ws, size_t ws_size,
                              hipStream_t stream) {
    const float* q  = (const float*)d_in[0];
    const float* k  = (const float*)d_in[1];
    const float* v  = (const float*)d_in[2];
    const float* kc = (const float*)d_in[3];
    const float* vc = (const float*)d_in[4];
    const int* cu   = (const int*)d_in[5];
    const int* slot = (const int*)d_in[6];

    float* out    = (float*)d_out;
    float* kc_out = out + (size_t)T_TOT * NH * DHEAD;
    float* vc_out = kc_out + (size_t)NSLOTS * NKV * DHEAD;

    // bf16 tile scratch lives in the cache-output region; attn reads it,
    // then copy/scatter overwrite it with the real cache outputs.
    char* kbf = (char*)kc_out;   // 8.4 MB used of 33.5 MB
    char* vbf = (char*)vc_out;

    prep_kv<<<dim3(NTILES, NKV), dim3(256), 0, stream>>>(k, v, kbf, vbf);
    attn_kernel<<<dim3(512), dim3(512), 0, stream>>>(q, kbf, vbf, cu, out);

    copy_cache<<<dim3((NSLOTS * NKV * DHEAD / 4) / 256), dim3(256), 0, stream>>>(
        (const float4*)kc, (const float4*)vc, (float4*)kc_out, (float4*)vc_out);
    scatter_kv<<<dim3((T_TOT * NKV * DHEAD / 4) / 256), dim3(256), 0, stream>>>(
        (const float4*)k, (const float4*)v, slot, (float4*)kc_out, (float4*)vc_out);
}